// Round 1
// baseline (187.833 us; speedup 1.0000x reference)
//
#include <hip/hip_runtime.h>
#include <cstddef>

// Problem constants (reference: N=16384, D=256, V=32000, T=128, decay=0.97)
namespace {
constexpr int Nn = 16384;
constexpr int Dd = 256;
constexpr int Tt = 128;
constexpr float DECAY = 0.97f;

// workspace layout (float offsets)
constexpr size_t WS_V    = 0;                          // V[t][d]      [128][256]
constexpr size_t WS_CUMV = WS_V + (size_t)Tt * Dd;     // cumV[s][d]   [128][256]
constexpr size_t WS_M    = WS_CUMV + (size_t)Tt * Dd;  // M[j][t]      [16384][128]
constexpr size_t WS_H    = WS_M + (size_t)Nn * Tt;     // h[s]         [128]
constexpr size_t WS_LNA  = WS_H + Tt;                  // ln(a_star)   [256]
constexpr size_t WS_U    = WS_LNA + Dd;                // u = E@y      [256]
}

// ---------------------------------------------------------------------------
// K0: gather token embeddings V[t][d] = token_emb[tokens[t]][d]; zero h[]
__global__ void k_gather(const float* __restrict__ temb, const int* __restrict__ toks,
                         float* __restrict__ Vb, float* __restrict__ h) {
  int t = blockIdx.x;
  int d = threadIdx.x;
  Vb[t * Dd + d] = temb[(size_t)toks[t] * Dd + d];
  if (blockIdx.x == 0 && threadIdx.x < Tt) h[threadIdx.x] = 0.f;
}

// K0b: cumV[s][d] = sum_{t>=s} 0.97^(T-t) * V[t][d]
__global__ void k_cumv(const float* __restrict__ Vb, float* __restrict__ cumV) {
  int d = threadIdx.x;  // 256 threads
  float run = 0.f, w = DECAY;
  for (int t = Tt - 1; t >= 0; --t) {
    run += w * Vb[t * Dd + d];
    cumV[t * Dd + d] = run;
    w *= DECAY;
  }
}

// ---------------------------------------------------------------------------
// K1: M[j][t] = relu( sum_k Dx[j][k] * V[t][k] ),  xf[j] = sum_t M[j][t]
// Tiled f32 GEMM: block tile 64(j) x 128(t), K=256 in chunks of 32.
// 256 threads = (tx 0..15 -> t micro 8) x (ty 0..15 -> j micro 4)
__global__ __launch_bounds__(256) void k_gemm_M(const float* __restrict__ Dx,
                                                const float* __restrict__ Vb,
                                                float* __restrict__ M,
                                                float* __restrict__ xf) {
  __shared__ __align__(16) float As[32 * 64];   // [k][j]
  __shared__ __align__(16) float Bs[32 * 128];  // [k][t]
  const int tid = threadIdx.x;
  const int tx = tid & 15, ty = tid >> 4;
  const int j0 = blockIdx.x * 64;
  float acc[4][8] = {};
  const float4* Dx4 = (const float4*)Dx;  // row stride 64 f4
  const float4* Vb4 = (const float4*)Vb;  // row stride 64 f4

  for (int ch = 0; ch < 8; ++ch) {
    __syncthreads();
    // stage Dx tile [64 j][32 k], transposed into As[k][j]
#pragma unroll
    for (int i = 0; i < 2; ++i) {
      int idx = tid + i * 256;           // 512 float4s
      int row = idx >> 3, k4 = idx & 7;  // 8 f4 per row
      float4 v = Dx4[(size_t)(j0 + row) * 64 + ch * 8 + k4];
      As[(k4 * 4 + 0) * 64 + row] = v.x;
      As[(k4 * 4 + 1) * 64 + row] = v.y;
      As[(k4 * 4 + 2) * 64 + row] = v.z;
      As[(k4 * 4 + 3) * 64 + row] = v.w;
    }
    // stage V tile [128 t][32 k], transposed into Bs[k][t]
#pragma unroll
    for (int i = 0; i < 4; ++i) {
      int idx = tid + i * 256;  // 1024 float4s
      int t = idx >> 3, k4 = idx & 7;
      float4 v = Vb4[(size_t)t * 64 + ch * 8 + k4];
      Bs[(k4 * 4 + 0) * 128 + t] = v.x;
      Bs[(k4 * 4 + 1) * 128 + t] = v.y;
      Bs[(k4 * 4 + 2) * 128 + t] = v.z;
      Bs[(k4 * 4 + 3) * 128 + t] = v.w;
    }
    __syncthreads();
#pragma unroll
    for (int kk = 0; kk < 32; ++kk) {
      float4 a = *(const float4*)&As[kk * 64 + ty * 4];
      float4 b0 = *(const float4*)&Bs[kk * 128 + tx * 8];
      float4 b1 = *(const float4*)&Bs[kk * 128 + tx * 8 + 4];
      float av[4] = {a.x, a.y, a.z, a.w};
      float bv[8] = {b0.x, b0.y, b0.z, b0.w, b1.x, b1.y, b1.z, b1.w};
#pragma unroll
      for (int r = 0; r < 4; ++r)
#pragma unroll
        for (int c = 0; c < 8; ++c) acc[r][c] += av[r] * bv[c];
    }
  }
  // relu, store M, accumulate row sums
  float rs[4];
#pragma unroll
  for (int r = 0; r < 4; ++r) {
    float s = 0.f;
#pragma unroll
    for (int c = 0; c < 8; ++c) {
      acc[r][c] = fmaxf(acc[r][c], 0.f);
      s += acc[r][c];
    }
    rs[r] = s;
    int j = j0 + ty * 4 + r;
    float4 o0 = {acc[r][0], acc[r][1], acc[r][2], acc[r][3]};
    float4 o1 = {acc[r][4], acc[r][5], acc[r][6], acc[r][7]};
    *(float4*)&M[(size_t)j * Tt + tx * 8] = o0;
    *(float4*)&M[(size_t)j * Tt + tx * 8 + 4] = o1;
  }
  __syncthreads();
  float* red = As;  // reuse: [64][17]
#pragma unroll
  for (int r = 0; r < 4; ++r) red[(ty * 4 + r) * 17 + tx] = rs[r];
  __syncthreads();
  if (tid < 64) {
    float s = 0.f;
#pragma unroll
    for (int x = 0; x < 16; ++x) s += red[tid * 17 + x];
    xf[j0 + tid] = s;  // x_{T-1}
  }
}

// ---------------------------------------------------------------------------
// K2: h[s] = sum_j M[j][s] * x_last[j]   (atomic partial sums per block)
__global__ void k_h(const float* __restrict__ M, const float* __restrict__ x,
                    float* __restrict__ h) {
  __shared__ float red[256];
  const int tid = threadIdx.x;
  const int s = tid & 127, half = tid >> 7;
  const int jbase = blockIdx.x * 64 + half * 32;
  float acc = 0.f;
  for (int i = 0; i < 32; ++i) {
    int j = jbase + i;
    acc += M[(size_t)j * Tt + s] * x[j];
  }
  red[tid] = acc;
  __syncthreads();
  if (tid < 128) atomicAdd(&h[tid], red[tid] + red[tid + 128]);
}

// ---------------------------------------------------------------------------
// K3: g = prefix(h); a_star[d] = sum_{t<=T-2} 0.97^(T-1-t) g[t] V[t][d]; ln_row
__global__ void k_astar(const float* __restrict__ h, const float* __restrict__ Vb,
                        float* __restrict__ lna) {
  __shared__ float g[Tt];
  __shared__ float red[256];
  const int d = threadIdx.x;  // 256
  if (d == 0) {
    float run = 0.f;
    for (int t = 0; t < Tt; ++t) {
      run += h[t];
      g[t] = run;  // g[t] = x_t . x_{T-1}
    }
  }
  __syncthreads();
  float a = 0.f, w = DECAY;
  for (int t = Tt - 2; t >= 0; --t) {
    a += w * g[t] * Vb[t * Dd + d];
    w *= DECAY;
  }
  // layernorm_row over 256 (unbiased std, eps added to std)
  red[d] = a;
  __syncthreads();
  for (int off = 128; off > 0; off >>= 1) {
    if (d < off) red[d] += red[d + off];
    __syncthreads();
  }
  float m = red[0] * (1.f / 256.f);
  __syncthreads();
  float c = a - m;
  red[d] = c * c;
  __syncthreads();
  for (int off = 128; off > 0; off >>= 1) {
    if (d < off) red[d] += red[d + off];
    __syncthreads();
  }
  float sd = sqrtf(red[0] * (1.f / 255.f));
  lna[d] = c / (sd + 1e-6f);
}

// ---------------------------------------------------------------------------
// K4: y[j] = relu( Dy[j] . lna ) * max(x[j], 0)   (one wave per row)
__global__ void k_y(const float* __restrict__ Dy, const float* __restrict__ lna,
                    const float* __restrict__ x, float* __restrict__ yout) {
  const int tid = threadIdx.x;
  const int wave = tid >> 6, lane = tid & 63;
  const int j = blockIdx.x * 4 + wave;
  const float4* Dy4 = (const float4*)Dy;
  const float4* l4 = (const float4*)lna;
  float4 a = Dy4[(size_t)j * 64 + lane];
  float4 b = l4[lane];
  float acc = a.x * b.x + a.y * b.y + a.z * b.z + a.w * b.w;
#pragma unroll
  for (int off = 32; off > 0; off >>= 1) acc += __shfl_down(acc, off);
  if (lane == 0) {
    yout[j] = fmaxf(acc, 0.f) * fmaxf(x[j], 0.f);
  }
}

// ---------------------------------------------------------------------------
// K5: u[d] = E[d] . y   (one block per d-row)
__global__ void k_u(const float* __restrict__ E, const float* __restrict__ y,
                    float* __restrict__ u) {
  __shared__ float red[256];
  const int d = blockIdx.x, tid = threadIdx.x;
  const float4* E4 = (const float4*)E;
  const float4* y4 = (const float4*)y;
  float acc = 0.f;
  for (int i = 0; i < 16; ++i) {
    int idx = tid + i * 256;  // 4096 f4 per row
    float4 e = E4[(size_t)d * 4096 + idx];
    float4 yv = y4[idx];
    acc += e.x * yv.x + e.y * yv.y + e.z * yv.z + e.w * yv.w;
  }
  red[tid] = acc;
  __syncthreads();
  for (int off = 128; off > 0; off >>= 1) {
    if (tid < off) red[tid] += red[tid + off];
    __syncthreads();
  }
  if (tid == 0) u[d] = red[0];
}

// K6: v_star = ln_row(u) -> out
__global__ void k_ln_u(const float* __restrict__ u, float* __restrict__ vout) {
  __shared__ float red[256];
  const int d = threadIdx.x;
  float a = u[d];
  red[d] = a;
  __syncthreads();
  for (int off = 128; off > 0; off >>= 1) {
    if (d < off) red[d] += red[d + off];
    __syncthreads();
  }
  float m = red[0] * (1.f / 256.f);
  __syncthreads();
  float c = a - m;
  red[d] = c * c;
  __syncthreads();
  for (int off = 128; off > 0; off >>= 1) {
    if (d < off) red[d] += red[d + off];
    __syncthreads();
  }
  float sd = sqrtf(red[0] * (1.f / 255.f));
  vout[d] = c / (sd + 1e-6f);
}

// ---------------------------------------------------------------------------
// K7: rho[d][j] = sum_s cumV[s][d] * M[j][s]
// block tile 64(d) x 128(j), K=128 in chunks of 32; 4 d-tiles x 128 j-tiles
__global__ __launch_bounds__(256) void k_rho(const float* __restrict__ cumV,
                                             const float* __restrict__ M,
                                             float* __restrict__ rho) {
  __shared__ __align__(16) float As[32 * 64];   // [k][d]
  __shared__ __align__(16) float Bs[32 * 128];  // [k][j]
  const int tid = threadIdx.x;
  const int tx = tid & 15, ty = tid >> 4;
  const int d0 = (blockIdx.x & 3) * 64;
  const int j0 = (blockIdx.x >> 2) * 128;
  float acc[4][8] = {};
  const float4* C4 = (const float4*)cumV;  // row stride 64 f4
  const float4* M4 = (const float4*)M;     // row stride 32 f4

  for (int ch = 0; ch < 4; ++ch) {
    __syncthreads();
    // stage cumV tile [32 k][64 d] directly (already [k][d])
#pragma unroll
    for (int i = 0; i < 2; ++i) {
      int idx = tid + i * 256;            // 512 f4
      int k = idx >> 4, d4 = idx & 15;    // 16 f4 per k-row
      float4 v = C4[(size_t)(ch * 32 + k) * 64 + (d0 >> 2) + d4];
      *(float4*)&As[k * 64 + d4 * 4] = v;
    }
    // stage M tile [128 j][32 k] transposed into Bs[k][j]
#pragma unroll
    for (int i = 0; i < 4; ++i) {
      int idx = tid + i * 256;  // 1024 f4
      int j = idx >> 3, k4 = idx & 7;
      float4 v = M4[(size_t)(j0 + j) * 32 + ch * 8 + k4];
      Bs[(k4 * 4 + 0) * 128 + j] = v.x;
      Bs[(k4 * 4 + 1) * 128 + j] = v.y;
      Bs[(k4 * 4 + 2) * 128 + j] = v.z;
      Bs[(k4 * 4 + 3) * 128 + j] = v.w;
    }
    __syncthreads();
#pragma unroll
    for (int kk = 0; kk < 32; ++kk) {
      float4 a = *(const float4*)&As[kk * 64 + ty * 4];
      float4 b0 = *(const float4*)&Bs[kk * 128 + tx * 8];
      float4 b1 = *(const float4*)&Bs[kk * 128 + tx * 8 + 4];
      float av[4] = {a.x, a.y, a.z, a.w};
      float bv[8] = {b0.x, b0.y, b0.z, b0.w, b1.x, b1.y, b1.z, b1.w};
#pragma unroll
      for (int r = 0; r < 4; ++r)
#pragma unroll
        for (int c = 0; c < 8; ++c) acc[r][c] += av[r] * bv[c];
    }
  }
#pragma unroll
  for (int r = 0; r < 4; ++r) {
    int d = d0 + ty * 4 + r;
    float4 o0 = {acc[r][0], acc[r][1], acc[r][2], acc[r][3]};
    float4 o1 = {acc[r][4], acc[r][5], acc[r][6], acc[r][7]};
    *(float4*)&rho[(size_t)d * Nn + j0 + tx * 8] = o0;
    *(float4*)&rho[(size_t)d * Nn + j0 + tx * 8 + 4] = o1;
  }
}

// ---------------------------------------------------------------------------
extern "C" void kernel_launch(void* const* d_in, const int* in_sizes, int n_in,
                              void* d_out, int out_size, void* d_ws, size_t ws_size,
                              hipStream_t stream) {
  const float* E = (const float*)d_in[0];     // [256][16384]
  const float* Dx = (const float*)d_in[1];    // [16384][256]
  const float* Dy = (const float*)d_in[2];    // [16384][256]
  const float* temb = (const float*)d_in[3];  // [32000][256]
  const int* toks = (const int*)d_in[4];      // [128]

  float* out = (float*)d_out;
  float* ws = (float*)d_ws;
  float* Vb   = ws + WS_V;
  float* cumV = ws + WS_CUMV;
  float* M    = ws + WS_M;
  float* h    = ws + WS_H;
  float* lna  = ws + WS_LNA;
  float* u    = ws + WS_U;

  float* xf  = out;                 // x_{T-1}          [16384]
  float* yv  = out + Nn;            // ys[-1]           [16384]
  float* vs  = out + 2 * Nn;        // vs[-1]           [256]
  float* rho = out + 2 * Nn + Dd;   // rho_f            [256*16384]

  k_gather<<<Tt, Dd, 0, stream>>>(temb, toks, Vb, h);
  k_cumv<<<1, Dd, 0, stream>>>(Vb, cumV);
  k_gemm_M<<<Nn / 64, 256, 0, stream>>>(Dx, Vb, M, xf);
  k_h<<<Nn / 64, 256, 0, stream>>>(M, xf, h);
  k_astar<<<1, Dd, 0, stream>>>(h, Vb, lna);
  k_y<<<Nn / 4, 256, 0, stream>>>(Dy, lna, xf, yv);
  k_u<<<Dd, 256, 0, stream>>>(E, yv, u);
  k_ln_u<<<1, Dd, 0, stream>>>(u, vs);
  k_rho<<<(Nn / 128) * 4, 256, 0, stream>>>(cumV, M, rho);
}